// Round 12
// baseline (267.992 us; speedup 1.0000x reference)
//
#include <hip/hip_runtime.h>
#include <math.h>

// x = (8, 3, 1024, 1024) f32, out = (8, 3, 1024, 1024) f32
constexpr int H = 1024, W = 1024, B = 8;
constexpr int NPIX = H * W;

typedef float f32x4 __attribute__((ext_vector_type(4)));

// ---------------- cross-image pipelined cooperative path ----------------
constexpr int PGRID = 512;             // persistent blocks, 2/CU; each owns 2 rows/image

__device__ __forceinline__ float grayat(const float* __restrict__ xb, int r, int c) {
    const float* p = xb + (size_t)r * W + c;
    return 0.3f * p[0] + 0.59f * p[NPIX] + 0.11f * p[2 * NPIX];
}
__device__ __forceinline__ void nt_store4(float* p, float x, float y, float z, float w) {
    f32x4 v = {x, y, z, w};
    __builtin_nontemporal_store(v, reinterpret_cast<f32x4*>(p));
}

union PackF2 { float2 f; unsigned long long u; };

// Persistent kernel: for b = 0..7, phase A(b) computes this block's 2 rows of
// image b (t kept in registers) and arrives on cnt[b]; phase B(b-1) then
// normalizes + writes the PREVIOUS image using its (already published) stats.
// Reads of image b and writes of image b-1 interleave in every wave's stream,
// so HBM sees both directions concurrently (the copy-bench regime, ~6.3 TB/s).
__global__ __launch_bounds__(256, 2)
void ltpe_pipe(const float* __restrict__ x, float* __restrict__ out,
               float2* __restrict__ part, unsigned* __restrict__ cnt)
{
    __shared__ float2 wred[4];
    const int blk  = blockIdx.x;          // 0..511
    const int r0   = blk * 2;             // this block's rows in every image
    const int tid  = threadIdx.x;
    const int lane = tid & 63;
    const int c    = tid << 2;

    constexpr float w0 = 1.f/255.f,  w1 = 2.f/255.f,  w2 = 4.f/255.f,  w3 = 8.f/255.f,
                    w4 = 16.f/255.f, w5 = 32.f/255.f, w6 = 64.f/255.f, w7 = 128.f/255.f;

    // ---- phase A for image b: returns un-normalized t rows in t0,t1 and
    //      publishes this block's partial, arriving on cnt[b]. ----
    auto phaseA = [&](int b, float4& t0, float4& t1) {
        const float* xb = x + (size_t)b * 3 * NPIX;

        // 12 predicated float4 loads (4 rows x 3 ch), all independent.
        float4 q[4][3];
        #pragma unroll
        for (int dr = 0; dr < 4; ++dr) {
            const int rr = r0 - 1 + dr;
            float4 z = {0.f, 0.f, 0.f, 0.f};
            q[dr][0] = z; q[dr][1] = z; q[dr][2] = z;
            if ((unsigned)rr < (unsigned)H) {
                const float* p = xb + (size_t)rr * W + c;
                q[dr][0] = *reinterpret_cast<const float4*>(p);
                q[dr][1] = *reinterpret_cast<const float4*>(p + NPIX);
                q[dr][2] = *reinterpret_cast<const float4*>(p + 2 * NPIX);
            }
        }
        // Edge-lane horizontal-halo patches.
        float pL[4], pR[4];
        #pragma unroll
        for (int dr = 0; dr < 4; ++dr) { pL[dr] = 0.f; pR[dr] = 0.f; }
        if (lane == 0 && c > 0) {
            #pragma unroll
            for (int dr = 0; dr < 4; ++dr) {
                const int rr = r0 - 1 + dr;
                if ((unsigned)rr < (unsigned)H) pL[dr] = grayat(xb, rr, c - 1);
            }
        }
        if (lane == 63 && c + 4 < W) {
            #pragma unroll
            for (int dr = 0; dr < 4; ++dr) {
                const int rr = r0 - 1 + dr;
                if ((unsigned)rr < (unsigned)H) pR[dr] = grayat(xb, rr, c + 4);
            }
        }

        // Gray rows, 6-wide: [0]=col c-1, [1..4]=c..c+3, [5]=c+4.
        float g[4][6];
        #pragma unroll
        for (int dr = 0; dr < 4; ++dr) {
            const float4 a = q[dr][0], d = q[dr][1], e = q[dr][2];
            g[dr][1] = 0.3f * a.x + 0.59f * d.x + 0.11f * e.x;
            g[dr][2] = 0.3f * a.y + 0.59f * d.y + 0.11f * e.y;
            g[dr][3] = 0.3f * a.z + 0.59f * d.z + 0.11f * e.z;
            g[dr][4] = 0.3f * a.w + 0.59f * d.w + 0.11f * e.w;
            float l  = __shfl_up(g[dr][4], 1);
            float rt = __shfl_down(g[dr][1], 1);
            if (lane == 0)  l  = pL[dr];
            if (lane == 63) rt = pR[dr];
            g[dr][0] = l; g[dr][5] = rt;
        }

        // Stencil rows 0,1. sum_j w_j == 1 => t = 0.5*(g+1) - 0.5*sum w_j nb_j
        float s = 0.f, ss = 0.f;
        float tv[2][4];
        #pragma unroll
        for (int j = 0; j < 2; ++j) {
            const float (&up)[6] = g[j];
            const float (&mi)[6] = g[j + 1];
            const float (&dn)[6] = g[j + 2];
            #pragma unroll
            for (int kk = 0; kk < 4; ++kk) {
                float sv = w0 * mi[kk];
                sv = fmaf(w1, dn[kk],     sv);
                sv = fmaf(w2, dn[kk + 1], sv);
                sv = fmaf(w3, dn[kk + 2], sv);
                sv = fmaf(w4, mi[kk + 2], sv);
                sv = fmaf(w5, up[kk + 2], sv);
                sv = fmaf(w6, up[kk + 1], sv);
                sv = fmaf(w7, up[kk],     sv);
                tv[j][kk] = 0.5f * mi[kk + 1] + 0.5f - 0.5f * sv;
                s += tv[j][kk];
                ss = fmaf(tv[j][kk], tv[j][kk], ss);
            }
        }
        t0 = make_float4(tv[0][0], tv[0][1], tv[0][2], tv[0][3]);
        t1 = make_float4(tv[1][0], tv[1][1], tv[1][2], tv[1][3]);

        // Block reduce -> publish partial, release-arrive on cnt[b].
        #pragma unroll
        for (int off = 32; off >= 1; off >>= 1) {
            s  += __shfl_down(s, off);
            ss += __shfl_down(ss, off);
        }
        if (lane == 0) wred[tid >> 6] = make_float2(s, ss);
        __syncthreads();
        if (tid == 0) {
            float2 a0 = wred[0], a1 = wred[1], a2 = wred[2], a3 = wred[3];
            PackF2 pk;
            pk.f = make_float2(a0.x + a1.x + a2.x + a3.x,
                               a0.y + a1.y + a2.y + a3.y);
            __hip_atomic_store(
                reinterpret_cast<unsigned long long*>(&part[(size_t)b * PGRID + blk]),
                pk.u, __ATOMIC_RELAXED, __HIP_MEMORY_SCOPE_AGENT);
            __hip_atomic_fetch_add(&cnt[b], 1u, __ATOMIC_RELEASE,
                                   __HIP_MEMORY_SCOPE_AGENT);
        }
        __syncthreads();   // also protects wred reuse next iteration
    };

    // ---- phase B for image b: spin (usually satisfied), reduce 512 partials
    //      (bit-identical in every block), normalize t rows, NT-write 3 ch. ----
    auto phaseB = [&](int b, float4 t0, float4 t1) {
        if (tid == 0) {
            while (__hip_atomic_load(&cnt[b], __ATOMIC_ACQUIRE,
                                     __HIP_MEMORY_SCOPE_AGENT) < (unsigned)PGRID) {
                __builtin_amdgcn_s_sleep(1);
            }
        }
        __syncthreads();

        const unsigned long long* pb =
            reinterpret_cast<const unsigned long long*>(part + (size_t)b * PGRID);
        double ds = 0.0, dss = 0.0;
        #pragma unroll
        for (int k = 0; k < 8; ++k) {
            PackF2 pv;
            pv.u = __hip_atomic_load(&pb[lane + 64 * k], __ATOMIC_RELAXED,
                                     __HIP_MEMORY_SCOPE_AGENT);
            ds  += (double)pv.f.x;
            dss += (double)pv.f.y;
        }
        #pragma unroll
        for (int o = 1; o <= 32; o <<= 1) {
            ds  += __shfl_xor(ds, o);
            dss += __shfl_xor(dss, o);
        }
        const double n     = (double)NPIX;
        const double dmean = ds / n;
        const double dvar  = dss / n - dmean * dmean;
        const float mean = (float)dmean;
        const float rstd = (float)(1.0 / sqrt(dvar + 1e-5));

        float* ob = out + (size_t)b * 3 * NPIX + (size_t)r0 * W + c;
        const float4 tt[2] = {t0, t1};
        #pragma unroll
        for (int j = 0; j < 2; ++j) {
            const float yx = (tt[j].x - mean) * rstd;
            const float yy = (tt[j].y - mean) * rstd;
            const float yz = (tt[j].z - mean) * rstd;
            const float yw = (tt[j].w - mean) * rstd;
            float* p = ob + (size_t)j * W;
            nt_store4(p,            yx, yy, yz, yw);
            nt_store4(p + NPIX,     yx, yy, yz, yw);
            nt_store4(p + 2 * NPIX, yx, yy, yz, yw);
        }
    };

    // ---- pipelined loop over images: A(b) then B(b-1); fully unrolled so all
    //      t registers have static indices. ----
    float4 tp0, tp1;                     // previous image's t
    {
        float4 t0, t1;
        phaseA(0, t0, t1);
        tp0 = t0; tp1 = t1;
    }
    #pragma unroll
    for (int b = 1; b < B; ++b) {
        float4 t0, t1;
        phaseA(b, t0, t1);               // reads of image b ...
        phaseB(b - 1, tp0, tp1);         // ... overlap writes of image b-1
        tp0 = t0; tp1 = t1;
    }
    phaseB(B - 1, tp0, tp1);
}

// ---------------- fallback: proven round-6 two-kernel pipeline ----------------
constexpr int ROWS = 2;
constexpr int RG   = H / ROWS;          // 512

__device__ __forceinline__ void gload16(const float* g, float* l) {
    __builtin_amdgcn_global_load_lds(
        (const __attribute__((address_space(1))) void*)g,
        (__attribute__((address_space(3))) void*)l, 16, 0, 0);
}

__global__ __launch_bounds__(256)
void ltpe_stage1(const float* __restrict__ x, float* __restrict__ out,
                 float2* __restrict__ part)
{
    __shared__ float lds[4][3][W];                // 48 KiB -> 3 blocks/CU
    const int b   = blockIdx.y;
    const int k   = blockIdx.x;
    const int kg  = ((k & 7) << 6) | (k >> 3);    // XCD-chunked bijective swizzle
    const int r0  = kg * ROWS;
    const int tid = threadIdx.x;
    const int w   = tid >> 6;
    const int l   = tid & 63;
    const int c   = tid << 2;
    const float* xb = x + (size_t)b * 3 * NPIX;

    #pragma unroll
    for (int s = 0; s < 4; ++s) {
        const int rr = r0 - 1 + s;
        if ((unsigned)rr < (unsigned)H) {
            #pragma unroll
            for (int ch = 0; ch < 3; ++ch) {
                const float* gp = xb + (size_t)ch * NPIX + (size_t)rr * W + (w << 8) + (l << 2);
                gload16(gp, &lds[s][ch][w << 8]);
            }
        } else {
            const float4 z = make_float4(0.f, 0.f, 0.f, 0.f);
            #pragma unroll
            for (int ch = 0; ch < 3; ++ch)
                *reinterpret_cast<float4*>(&lds[s][ch][c]) = z;
        }
    }
    __syncthreads();

    const int ql = (tid == 0)   ? 0   : tid - 1;
    const int qr = (tid == 255) ? 255 : tid + 1;
    float g6[4][6];
    #pragma unroll
    for (int s = 0; s < 4; ++s) {
        const float4 o0 = *reinterpret_cast<const float4*>(&lds[s][0][c]);
        const float4 o1 = *reinterpret_cast<const float4*>(&lds[s][1][c]);
        const float4 o2 = *reinterpret_cast<const float4*>(&lds[s][2][c]);
        const float4 l0 = *reinterpret_cast<const float4*>(&lds[s][0][ql << 2]);
        const float4 l1 = *reinterpret_cast<const float4*>(&lds[s][1][ql << 2]);
        const float4 l2 = *reinterpret_cast<const float4*>(&lds[s][2][ql << 2]);
        const float4 rq0 = *reinterpret_cast<const float4*>(&lds[s][0][qr << 2]);
        const float4 rq1 = *reinterpret_cast<const float4*>(&lds[s][1][qr << 2]);
        const float4 rq2 = *reinterpret_cast<const float4*>(&lds[s][2][qr << 2]);
        g6[s][1] = 0.3f * o0.x + 0.59f * o1.x + 0.11f * o2.x;
        g6[s][2] = 0.3f * o0.y + 0.59f * o1.y + 0.11f * o2.y;
        g6[s][3] = 0.3f * o0.z + 0.59f * o1.z + 0.11f * o2.z;
        g6[s][4] = 0.3f * o0.w + 0.59f * o1.w + 0.11f * o2.w;
        g6[s][0] = (tid == 0)   ? 0.f : 0.3f * l0.w  + 0.59f * l1.w  + 0.11f * l2.w;
        g6[s][5] = (tid == 255) ? 0.f : 0.3f * rq0.x + 0.59f * rq1.x + 0.11f * rq2.x;
    }

    constexpr float w0 = 1.f/255.f,  w1 = 2.f/255.f,  w2 = 4.f/255.f,  w3 = 8.f/255.f,
                    w4 = 16.f/255.f, w5 = 32.f/255.f, w6 = 64.f/255.f, w7 = 128.f/255.f;
    float s = 0.f, ss = 0.f;
    float* ob = out + (size_t)b * 3 * NPIX + (size_t)r0 * W + c;
    #pragma unroll
    for (int rr = 0; rr < ROWS; ++rr) {
        const float (&up)[6] = g6[rr];
        const float (&mi)[6] = g6[rr + 1];
        const float (&dn)[6] = g6[rr + 2];
        float tv[4];
        #pragma unroll
        for (int kk = 0; kk < 4; ++kk) {
            float sv = w0 * mi[kk];
            sv = fmaf(w1, dn[kk],     sv);
            sv = fmaf(w2, dn[kk + 1], sv);
            sv = fmaf(w3, dn[kk + 2], sv);
            sv = fmaf(w4, mi[kk + 2], sv);
            sv = fmaf(w5, up[kk + 2], sv);
            sv = fmaf(w6, up[kk + 1], sv);
            sv = fmaf(w7, up[kk],     sv);
            tv[kk] = 0.5f * mi[kk + 1] + 0.5f - 0.5f * sv;
            s += tv[kk];
            ss = fmaf(tv[kk], tv[kk], ss);
        }
        float4 t4 = {tv[0], tv[1], tv[2], tv[3]};
        *reinterpret_cast<float4*>(ob + (size_t)rr * W) = t4;
    }

    #pragma unroll
    for (int off = 32; off >= 1; off >>= 1) {
        s  += __shfl_down(s, off);
        ss += __shfl_down(ss, off);
    }
    __shared__ float2 wred[4];
    if (l == 0) wred[w] = make_float2(s, ss);
    __syncthreads();
    if (tid == 0) {
        float2 a0 = wred[0], a1 = wred[1], a2 = wred[2], a3 = wred[3];
        part[(size_t)b * RG + kg] = make_float2(a0.x + a1.x + a2.x + a3.x,
                                                a0.y + a1.y + a2.y + a3.y);
    }
}

__global__ __launch_bounds__(256)
void ltpe_stageB(float* __restrict__ out, const float2* __restrict__ part)
{
    const int b    = blockIdx.y;
    const int r    = blockIdx.x;
    const int tid  = threadIdx.x;
    const int lane = tid & 63;

    const float4* pp = reinterpret_cast<const float4*>(part + (size_t)b * RG);
    const float4 u = pp[tid];
    double s  = (double)u.x + (double)u.z;
    double ss = (double)u.y + (double)u.w;
    #pragma unroll
    for (int off = 32; off >= 1; off >>= 1) {
        s  += __shfl_down(s, off);
        ss += __shfl_down(ss, off);
    }
    __shared__ double red[8];
    __shared__ float2 mv;
    const int wv = tid >> 6;
    if (lane == 0) { red[wv] = s; red[4 + wv] = ss; }
    __syncthreads();
    if (tid == 0) {
        const double S  = red[0] + red[1] + red[2] + red[3];
        const double SS = red[4] + red[5] + red[6] + red[7];
        const double n    = (double)NPIX;
        const double mean = S / n;
        const double var  = SS / n - mean * mean;
        mv = make_float2((float)mean, (float)(1.0 / sqrt(var + 1e-5)));
    }
    __syncthreads();
    const float mean = mv.x, rstd = mv.y;

    const size_t base = (size_t)b * 3 * NPIX + (size_t)r * W + (tid << 2);
    const float4 t4 = *reinterpret_cast<const float4*>(out + base);
    float4 y;
    y.x = (t4.x - mean) * rstd;
    y.y = (t4.y - mean) * rstd;
    y.z = (t4.z - mean) * rstd;
    y.w = (t4.w - mean) * rstd;
    *reinterpret_cast<float4*>(out + base)            = y;
    *reinterpret_cast<float4*>(out + base + NPIX)     = y;
    *reinterpret_cast<float4*>(out + base + 2 * NPIX) = y;
}

extern "C" void kernel_launch(void* const* d_in, const int* in_sizes, int n_in,
                              void* d_out, int out_size, void* d_ws, size_t ws_size,
                              hipStream_t stream)
{
    const float* x = (const float*)d_in[0];
    float* out = (float*)d_out;
    float2* part = (float2*)d_ws;                       // 8*512 float2 = 32 KiB
    unsigned* cnt = (unsigned*)((char*)d_ws + 32768);   // 8 arrival counters

    int nb = 0;
    hipError_t qe = hipOccupancyMaxActiveBlocksPerMultiprocessor(
        &nb, reinterpret_cast<const void*>(ltpe_pipe), 256, 0);

    if (qe == hipSuccess && nb * 256 >= PGRID) {
        (void)hipMemsetAsync(cnt, 0, 8 * sizeof(unsigned), stream);
        void* args[] = { (void*)&x, (void*)&out, (void*)&part, (void*)&cnt };
        (void)hipLaunchCooperativeKernel((void*)ltpe_pipe, dim3(PGRID), dim3(256),
                                         args, 0, stream);
    } else {
        ltpe_stage1<<<dim3(RG, B), 256, 0, stream>>>(x, out, part);
        ltpe_stageB<<<dim3(H, B), 256, 0, stream>>>(out, part);
    }
}

// Round 13
// 50.863 us; speedup vs baseline: 5.2689x; 5.2689x over previous
//
#include <hip/hip_runtime.h>
#include <hip/hip_cooperative_groups.h>
#include <math.h>

namespace cg = cooperative_groups;

// x = (8, 3, 1024, 1024) f32, out = (8, 3, 1024, 1024) f32
constexpr int H = 1024, W = 1024, B = 8;
constexpr int NPIX = H * W;

// ---------------- fused cooperative path (round-8 best: 50.89 us) ----------------
constexpr int FR    = 16;              // rows per block
constexpr int GPB   = H / FR;          // 64 row-groups (blocks) per image
constexpr int FGRID = B * GPB;         // 512 blocks = 2/CU on 256 CUs

__device__ __forceinline__ void gload16(const float* g, float* l) {
    __builtin_amdgcn_global_load_lds(
        (const __attribute__((address_space(1))) void*)g,
        (__attribute__((address_space(3))) void*)l, 16, 0, 0);
}
__device__ __forceinline__ float grayat(const float* __restrict__ xb, int r, int c) {
    const float* p = xb + (size_t)r * W + c;
    return 0.3f * p[0] + 0.59f * p[NPIX] + 0.11f * p[2 * NPIX];
}

// One fused kernel. Phase A: per-wave pipelined staging (5-slot LDS ring,
// counted vmcnt, no barriers) -> gray -> stencil -> t in 16 float4 regs +
// per-block partial. grid.sync. Phase B: butterfly-reduce 64 partials/image
// (identical in every lane), normalize regs, write 3 replicated channels.
__global__ __launch_bounds__(256, 2)
void ltpe_fused(const float* __restrict__ x, float* __restrict__ out,
                float2* __restrict__ part)
{
    __shared__ float lds[4][5][3][256];   // per-wave ring: 5 slots x 3 ch x 256 cols
    __shared__ float2 wred[4];

    const int blk  = blockIdx.x;
    const int b    = blk & 7;             // image pinned to XCD (round-robin dispatch)
    const int g    = blk >> 3;            // row-group 0..63
    const int r0   = g * FR;
    const int tid  = threadIdx.x;
    const int w    = tid >> 6;
    const int lane = tid & 63;
    const int c    = tid << 2;            // global column quad
    const float* xb = x + (size_t)b * 3 * NPIX;
    float (*ldsw)[3][256] = lds[w];       // this wave's private ring

    constexpr float w0 = 1.f/255.f,  w1 = 2.f/255.f,  w2 = 4.f/255.f,  w3 = 8.f/255.f,
                    w4 = 16.f/255.f, w5 = 32.f/255.f, w6 = 64.f/255.f, w7 = 128.f/255.f;

    // Prologue: edge-lane horizontal-halo gray values into registers, so the
    // steady-state loop has NO vmem other than global_load_lds (exact vmcnt).
    float pL[FR + 2], pR[FR + 2];
    #pragma unroll
    for (int i = 0; i < FR + 2; ++i) { pL[i] = 0.f; pR[i] = 0.f; }
    if (lane == 0 && c > 0) {
        #pragma unroll
        for (int i = 0; i < FR + 2; ++i) {
            const int rr = r0 - 1 + i;
            if ((unsigned)rr < (unsigned)H) pL[i] = grayat(xb, rr, c - 1);
        }
    }
    if (lane == 63 && c + 4 < W) {
        #pragma unroll
        for (int i = 0; i < FR + 2; ++i) {
            const int rr = r0 - 1 + i;
            if ((unsigned)rr < (unsigned)H) pR[i] = grayat(xb, rr, c + 4);
        }
    }
    __builtin_amdgcn_sched_barrier(0);    // keep patch loads fully before staging

    // Stage row-offset `off` (row r0-1+off, CLAMPED so every block issues the
    // same gload count; garbage rows are zeroed at gray time) into ring slot.
    auto stage = [&](int off, int slot) {
        int rr = r0 - 1 + off;
        rr = rr < 0 ? 0 : (rr > H - 1 ? H - 1 : rr);
        const float* gp = xb + (size_t)rr * W + (w << 8) + (lane << 2);
        gload16(gp,            &ldsw[slot][0][0]);
        gload16(gp + NPIX,     &ldsw[slot][1][0]);
        gload16(gp + 2*NPIX,   &ldsw[slot][2][0]);
    };

    // Gray (6-wide) for row-offset `off` from ring slot.
    auto grayc = [&](int off, int slot, float (&d)[6]) {
        const bool rok = (unsigned)(r0 - 1 + off) < (unsigned)H;
        const float4 a = *reinterpret_cast<const float4*>(&ldsw[slot][0][lane << 2]);
        const float4 e = *reinterpret_cast<const float4*>(&ldsw[slot][1][lane << 2]);
        const float4 f = *reinterpret_cast<const float4*>(&ldsw[slot][2][lane << 2]);
        float g1 = 0.3f*a.x + 0.59f*e.x + 0.11f*f.x;
        float g2 = 0.3f*a.y + 0.59f*e.y + 0.11f*f.y;
        float g3 = 0.3f*a.z + 0.59f*e.z + 0.11f*f.z;
        float g4 = 0.3f*a.w + 0.59f*e.w + 0.11f*f.w;
        float glv = __shfl_up(g4, 1);
        float grv = __shfl_down(g1, 1);
        if (lane == 0)  glv = pL[off];
        if (lane == 63) grv = pR[off];
        if (!rok) { g1 = g2 = g3 = g4 = glv = grv = 0.f; }   // zero-pad row
        d[0]=glv; d[1]=g1; d[2]=g2; d[3]=g3; d[4]=g4; d[5]=grv;
    };

    float gr6[3][6];
    float4 tq[FR];                        // un-normalized t, lives in VGPRs
    float s = 0.f, ss = 0.f;

    // Pipeline prologue: offsets 0..3 staged (12 gloads); wait oldest 6.
    stage(0, 0); stage(1, 1); stage(2, 2); stage(3, 3);
    asm volatile("s_waitcnt vmcnt(6)" ::: "memory");
    __builtin_amdgcn_sched_barrier(0);
    grayc(0, 0, gr6[0]);
    grayc(1, 1, gr6[1]);

    // Step I: issue offset I+4 (3 gloads), wait so offset I+2 is resident
    // (outstanding = offsets I+3, I+4 = 6), gray(I+2), stencil output row r0+I.
#define LTPE_STEP(I, WAITSTR)                                                  \
    {                                                                          \
        if ((I) + 4 <= FR + 1) stage((I) + 4, ((I) + 4) % 5);                  \
        asm volatile(WAITSTR ::: "memory");                                    \
        __builtin_amdgcn_sched_barrier(0);                                     \
        grayc((I) + 2, ((I) + 2) % 5, gr6[((I) + 2) % 3]);                     \
        const float (&up)[6] = gr6[(I) % 3];                                   \
        const float (&mi)[6] = gr6[((I) + 1) % 3];                             \
        const float (&dn)[6] = gr6[((I) + 2) % 3];                             \
        float tv[4];                                                           \
        _Pragma("unroll")                                                      \
        for (int kk = 0; kk < 4; ++kk) {                                       \
            float sv = w0 * mi[kk];                                            \
            sv = fmaf(w1, dn[kk],     sv);                                     \
            sv = fmaf(w2, dn[kk + 1], sv);                                     \
            sv = fmaf(w3, dn[kk + 2], sv);                                     \
            sv = fmaf(w4, mi[kk + 2], sv);                                     \
            sv = fmaf(w5, up[kk + 2], sv);                                     \
            sv = fmaf(w6, up[kk + 1], sv);                                     \
            sv = fmaf(w7, up[kk],     sv);                                     \
            tv[kk] = 0.5f * mi[kk + 1] + 0.5f - 0.5f * sv;                     \
            s += tv[kk];                                                       \
            ss = fmaf(tv[kk], tv[kk], ss);                                     \
        }                                                                      \
        tq[I] = make_float4(tv[0], tv[1], tv[2], tv[3]);                       \
    }

    LTPE_STEP(0,  "s_waitcnt vmcnt(6)")
    LTPE_STEP(1,  "s_waitcnt vmcnt(6)")
    LTPE_STEP(2,  "s_waitcnt vmcnt(6)")
    LTPE_STEP(3,  "s_waitcnt vmcnt(6)")
    LTPE_STEP(4,  "s_waitcnt vmcnt(6)")
    LTPE_STEP(5,  "s_waitcnt vmcnt(6)")
    LTPE_STEP(6,  "s_waitcnt vmcnt(6)")
    LTPE_STEP(7,  "s_waitcnt vmcnt(6)")
    LTPE_STEP(8,  "s_waitcnt vmcnt(6)")
    LTPE_STEP(9,  "s_waitcnt vmcnt(6)")
    LTPE_STEP(10, "s_waitcnt vmcnt(6)")
    LTPE_STEP(11, "s_waitcnt vmcnt(6)")
    LTPE_STEP(12, "s_waitcnt vmcnt(6)")
    LTPE_STEP(13, "s_waitcnt vmcnt(6)")
    LTPE_STEP(14, "s_waitcnt vmcnt(3)")
    LTPE_STEP(15, "s_waitcnt vmcnt(0)")
#undef LTPE_STEP

    // Block reduce -> one fp32 partial pair per block.
    #pragma unroll
    for (int off = 32; off >= 1; off >>= 1) {
        s  += __shfl_down(s, off);
        ss += __shfl_down(ss, off);
    }
    if (lane == 0) wred[w] = make_float2(s, ss);
    __syncthreads();
    if (tid == 0) {
        float2 a0 = wred[0], a1 = wred[1], a2 = wred[2], a3 = wred[3];
        part[(size_t)b * GPB + g] = make_float2(a0.x + a1.x + a2.x + a3.x,
                                                a0.y + a1.y + a2.y + a3.y);
    }

    cg::this_grid().sync();

    // Phase B: butterfly-reduce the image's 64 partials (one per lane) in double.
    const float2 pv = part[(size_t)b * GPB + lane];
    double ds = (double)pv.x, dss = (double)pv.y;
    #pragma unroll
    for (int o = 1; o <= 32; o <<= 1) {
        ds  += __shfl_xor(ds, o);
        dss += __shfl_xor(dss, o);
    }
    const double n     = (double)NPIX;
    const double dmean = ds / n;
    const double dvar  = dss / n - dmean * dmean;
    const float mean = (float)dmean;
    const float rstd = (float)(1.0 / sqrt(dvar + 1e-5));

    float* ob = out + (size_t)b * 3 * NPIX + (size_t)r0 * W + c;
    #pragma unroll
    for (int i = 0; i < FR; ++i) {
        const float4 t4 = tq[i];
        float4 y;
        y.x = (t4.x - mean) * rstd;
        y.y = (t4.y - mean) * rstd;
        y.z = (t4.z - mean) * rstd;
        y.w = (t4.w - mean) * rstd;
        float* p = ob + (size_t)i * W;
        *reinterpret_cast<float4*>(p)            = y;
        *reinterpret_cast<float4*>(p + NPIX)     = y;
        *reinterpret_cast<float4*>(p + 2 * NPIX) = y;
    }
}

// ---------------- fallback: proven round-6 two-kernel pipeline ----------------
constexpr int ROWS = 2;
constexpr int RG   = H / ROWS;          // 512

__global__ __launch_bounds__(256)
void ltpe_stage1(const float* __restrict__ x, float* __restrict__ out,
                 float2* __restrict__ part)
{
    __shared__ float lds[4][3][W];                // 48 KiB -> 3 blocks/CU
    const int b   = blockIdx.y;
    const int k   = blockIdx.x;
    const int kg  = ((k & 7) << 6) | (k >> 3);    // XCD-chunked bijective swizzle
    const int r0  = kg * ROWS;
    const int tid = threadIdx.x;
    const int w   = tid >> 6;
    const int l   = tid & 63;
    const int c   = tid << 2;
    const float* xb = x + (size_t)b * 3 * NPIX;

    #pragma unroll
    for (int s = 0; s < 4; ++s) {
        const int rr = r0 - 1 + s;
        if ((unsigned)rr < (unsigned)H) {
            #pragma unroll
            for (int ch = 0; ch < 3; ++ch) {
                const float* gp = xb + (size_t)ch * NPIX + (size_t)rr * W + (w << 8) + (l << 2);
                gload16(gp, &lds[s][ch][w << 8]);
            }
        } else {
            const float4 z = make_float4(0.f, 0.f, 0.f, 0.f);
            #pragma unroll
            for (int ch = 0; ch < 3; ++ch)
                *reinterpret_cast<float4*>(&lds[s][ch][c]) = z;
        }
    }
    __syncthreads();

    const int ql = (tid == 0)   ? 0   : tid - 1;
    const int qr = (tid == 255) ? 255 : tid + 1;
    float g6[4][6];
    #pragma unroll
    for (int s = 0; s < 4; ++s) {
        const float4 o0 = *reinterpret_cast<const float4*>(&lds[s][0][c]);
        const float4 o1 = *reinterpret_cast<const float4*>(&lds[s][1][c]);
        const float4 o2 = *reinterpret_cast<const float4*>(&lds[s][2][c]);
        const float4 l0 = *reinterpret_cast<const float4*>(&lds[s][0][ql << 2]);
        const float4 l1 = *reinterpret_cast<const float4*>(&lds[s][1][ql << 2]);
        const float4 l2 = *reinterpret_cast<const float4*>(&lds[s][2][ql << 2]);
        const float4 rq0 = *reinterpret_cast<const float4*>(&lds[s][0][qr << 2]);
        const float4 rq1 = *reinterpret_cast<const float4*>(&lds[s][1][qr << 2]);
        const float4 rq2 = *reinterpret_cast<const float4*>(&lds[s][2][qr << 2]);
        g6[s][1] = 0.3f * o0.x + 0.59f * o1.x + 0.11f * o2.x;
        g6[s][2] = 0.3f * o0.y + 0.59f * o1.y + 0.11f * o2.y;
        g6[s][3] = 0.3f * o0.z + 0.59f * o1.z + 0.11f * o2.z;
        g6[s][4] = 0.3f * o0.w + 0.59f * o1.w + 0.11f * o2.w;
        g6[s][0] = (tid == 0)   ? 0.f : 0.3f * l0.w  + 0.59f * l1.w  + 0.11f * l2.w;
        g6[s][5] = (tid == 255) ? 0.f : 0.3f * rq0.x + 0.59f * rq1.x + 0.11f * rq2.x;
    }

    constexpr float w0 = 1.f/255.f,  w1 = 2.f/255.f,  w2 = 4.f/255.f,  w3 = 8.f/255.f,
                    w4 = 16.f/255.f, w5 = 32.f/255.f, w6 = 64.f/255.f, w7 = 128.f/255.f;
    float s = 0.f, ss = 0.f;
    float* ob = out + (size_t)b * 3 * NPIX + (size_t)r0 * W + c;
    #pragma unroll
    for (int rr = 0; rr < ROWS; ++rr) {
        const float (&up)[6] = g6[rr];
        const float (&mi)[6] = g6[rr + 1];
        const float (&dn)[6] = g6[rr + 2];
        float tv[4];
        #pragma unroll
        for (int kk = 0; kk < 4; ++kk) {
            float sv = w0 * mi[kk];
            sv = fmaf(w1, dn[kk],     sv);
            sv = fmaf(w2, dn[kk + 1], sv);
            sv = fmaf(w3, dn[kk + 2], sv);
            sv = fmaf(w4, mi[kk + 2], sv);
            sv = fmaf(w5, up[kk + 2], sv);
            sv = fmaf(w6, up[kk + 1], sv);
            sv = fmaf(w7, up[kk],     sv);
            tv[kk] = 0.5f * mi[kk + 1] + 0.5f - 0.5f * sv;
            s += tv[kk];
            ss = fmaf(tv[kk], tv[kk], ss);
        }
        float4 t4 = {tv[0], tv[1], tv[2], tv[3]};
        *reinterpret_cast<float4*>(ob + (size_t)rr * W) = t4;
    }

    #pragma unroll
    for (int off = 32; off >= 1; off >>= 1) {
        s  += __shfl_down(s, off);
        ss += __shfl_down(ss, off);
    }
    __shared__ float2 wred[4];
    if (l == 0) wred[w] = make_float2(s, ss);
    __syncthreads();
    if (tid == 0) {
        float2 a0 = wred[0], a1 = wred[1], a2 = wred[2], a3 = wred[3];
        part[(size_t)b * RG + kg] = make_float2(a0.x + a1.x + a2.x + a3.x,
                                                a0.y + a1.y + a2.y + a3.y);
    }
}

__global__ __launch_bounds__(256)
void ltpe_stageB(float* __restrict__ out, const float2* __restrict__ part)
{
    const int b    = blockIdx.y;
    const int r    = blockIdx.x;
    const int tid  = threadIdx.x;
    const int lane = tid & 63;

    const float4* pp = reinterpret_cast<const float4*>(part + (size_t)b * RG);
    const float4 u = pp[tid];
    double s  = (double)u.x + (double)u.z;
    double ss = (double)u.y + (double)u.w;
    #pragma unroll
    for (int off = 32; off >= 1; off >>= 1) {
        s  += __shfl_down(s, off);
        ss += __shfl_down(ss, off);
    }
    __shared__ double red[8];
    __shared__ float2 mv;
    const int wv = tid >> 6;
    if (lane == 0) { red[wv] = s; red[4 + wv] = ss; }
    __syncthreads();
    if (tid == 0) {
        const double S  = red[0] + red[1] + red[2] + red[3];
        const double SS = red[4] + red[5] + red[6] + red[7];
        const double n    = (double)NPIX;
        const double mean = S / n;
        const double var  = SS / n - mean * mean;
        mv = make_float2((float)mean, (float)(1.0 / sqrt(var + 1e-5)));
    }
    __syncthreads();
    const float mean = mv.x, rstd = mv.y;

    const size_t base = (size_t)b * 3 * NPIX + (size_t)r * W + (tid << 2);
    const float4 t4 = *reinterpret_cast<const float4*>(out + base);
    float4 y;
    y.x = (t4.x - mean) * rstd;
    y.y = (t4.y - mean) * rstd;
    y.z = (t4.z - mean) * rstd;
    y.w = (t4.w - mean) * rstd;
    *reinterpret_cast<float4*>(out + base)            = y;
    *reinterpret_cast<float4*>(out + base + NPIX)     = y;
    *reinterpret_cast<float4*>(out + base + 2 * NPIX) = y;
}

extern "C" void kernel_launch(void* const* d_in, const int* in_sizes, int n_in,
                              void* d_out, int out_size, void* d_ws, size_t ws_size,
                              hipStream_t stream)
{
    const float* x = (const float*)d_in[0];
    float* out = (float*)d_out;
    float2* part = (float2*)d_ws;   // fused: 512 float2; fallback: 4096 float2

    int nb = 0;
    hipError_t qe = hipOccupancyMaxActiveBlocksPerMultiprocessor(
        &nb, reinterpret_cast<const void*>(ltpe_fused), 256, 0);

    if (qe == hipSuccess && nb * 256 >= FGRID) {
        void* args[] = { (void*)&x, (void*)&out, (void*)&part };
        (void)hipLaunchCooperativeKernel((void*)ltpe_fused, dim3(FGRID), dim3(256),
                                         args, 0, stream);
    } else {
        ltpe_stage1<<<dim3(RG, B), 256, 0, stream>>>(x, out, part);
        ltpe_stageB<<<dim3(H, B), 256, 0, stream>>>(out, part);
    }
}